// Round 9
// baseline (433.500 us; speedup 1.0000x reference)
//
#include <hip/hip_runtime.h>

#define N 8192
#define D 512

typedef __attribute__((ext_vector_type(8))) short short8;
typedef __attribute__((ext_vector_type(4))) float f32x4;

typedef const __attribute__((address_space(1))) unsigned int* gas_t;
typedef __attribute__((address_space(3))) unsigned int* las_t;

static __device__ __forceinline__ unsigned short f2bf(float f) {
    unsigned u = __float_as_uint(f);
    unsigned r = (u + 0x7FFFu + ((u >> 16) & 1u)) >> 16;
    return (unsigned short)r;
}
static __device__ __forceinline__ float bf2f(unsigned u) {
    return __uint_as_float(u << 16);
}
static __device__ __forceinline__ void gl_lds16(const unsigned short* g, char* l) {
    __builtin_amdgcn_global_load_lds((gas_t)g, (las_t)l, 16, 0, 0);
}
static __device__ __forceinline__ int tc32(int r) { return r * (65 - r) / 2; }

// K1: row-normalize embeddings -> bf16 e[N][D], PRE-SCALED by sqrt(10*log2(e))
// so the GEMM accumulator is directly the exp2 argument. Also packs thetas.
__global__ void knorm(const float* __restrict__ emb, unsigned short* __restrict__ e,
                      const float* __restrict__ th, float4* __restrict__ th4,
                      float* __restrict__ srow, unsigned* __restrict__ jminrow,
                      unsigned* __restrict__ negrow, unsigned* __restrict__ d2mb) {
    int row  = blockIdx.x * 4 + (threadIdx.x >> 6);
    int lane = threadIdx.x & 63;
    const float4* src = (const float4*)(emb + (size_t)row * D);
    float4 v0 = src[lane * 2];
    float4 v1 = src[lane * 2 + 1];
    float ss = v0.x*v0.x + v0.y*v0.y + v0.z*v0.z + v0.w*v0.w
             + v1.x*v1.x + v1.y*v1.y + v1.z*v1.z + v1.w*v1.w;
#pragma unroll
    for (int off = 1; off < 64; off <<= 1) ss += __shfl_xor(ss, off, 64);
    float inv = 3.7982826f / fmaxf(sqrtf(ss), 1e-12f);
    unsigned short h0 = f2bf(v0.x * inv), h1 = f2bf(v0.y * inv);
    unsigned short h2 = f2bf(v0.z * inv), h3 = f2bf(v0.w * inv);
    unsigned short h4 = f2bf(v1.x * inv), h5 = f2bf(v1.y * inv);
    unsigned short h6 = f2bf(v1.z * inv), h7 = f2bf(v1.w * inv);
    uint4 pk;
    pk.x = (unsigned)h0 | ((unsigned)h1 << 16);
    pk.y = (unsigned)h2 | ((unsigned)h3 << 16);
    pk.z = (unsigned)h4 | ((unsigned)h5 << 16);
    pk.w = (unsigned)h6 | ((unsigned)h7 << 16);
    ((uint4*)(e + (size_t)row * D))[lane] = pk;

    int tid = threadIdx.x;
    if (tid < 4) {
        int i = blockIdx.x * 4 + tid;
        float x = th[3 * i], y = th[3 * i + 1], z = th[3 * i + 2];
        float4 v; v.x = x; v.y = y; v.z = z; v.w = x * x + y * y + z * z;
        th4[i] = v;
        srow[i] = 0.0f;
        jminrow[i] = 0xFFFFFFFFu;
        negrow[i] = 0u;
    }
    if (blockIdx.x == 0 && tid == 0) *d2mb = 0u;
}

// K3: global max of squared pairwise theta distance (8 rows per wave in regs).
__global__ void kd2max(const float4* __restrict__ th4, unsigned* __restrict__ d2mb) {
    int widx = blockIdx.x * 4 + (threadIdx.x >> 6);
    int lane = threadIdx.x & 63;
    int q0 = widx * 4;
    int m0 = N - 4 - q0;
    float4 a0 = th4[q0], a1 = th4[q0 + 1], a2 = th4[q0 + 2], a3 = th4[q0 + 3];
    float4 b0 = th4[m0], b1 = th4[m0 + 1], b2 = th4[m0 + 2], b3 = th4[m0 + 3];
    float m = 0.0f;
    for (int j = q0 + 1 + lane; j < N; j += 64) {
        float4 tj = th4[j];
        float d;
        d = a0.w + tj.w - 2.0f * (a0.x*tj.x + a0.y*tj.y + a0.z*tj.z); m = fmaxf(m, d);
        d = a1.w + tj.w - 2.0f * (a1.x*tj.x + a1.y*tj.y + a1.z*tj.z); m = fmaxf(m, d);
        d = a2.w + tj.w - 2.0f * (a2.x*tj.x + a2.y*tj.y + a2.z*tj.z); m = fmaxf(m, d);
        d = a3.w + tj.w - 2.0f * (a3.x*tj.x + a3.y*tj.y + a3.z*tj.z); m = fmaxf(m, d);
    }
    for (int j = m0 + 1 + lane; j < N; j += 64) {
        float4 tj = th4[j];
        float d;
        d = b0.w + tj.w - 2.0f * (b0.x*tj.x + b0.y*tj.y + b0.z*tj.z); m = fmaxf(m, d);
        d = b1.w + tj.w - 2.0f * (b1.x*tj.x + b1.y*tj.y + b1.z*tj.z); m = fmaxf(m, d);
        d = b2.w + tj.w - 2.0f * (b2.x*tj.x + b2.y*tj.y + b2.z*tj.z); m = fmaxf(m, d);
        d = b3.w + tj.w - 2.0f * (b3.x*tj.x + b3.y*tj.y + b3.z*tj.z); m = fmaxf(m, d);
    }
#pragma unroll
    for (int off = 1; off < 64; off <<= 1) m = fmaxf(m, __shfl_xor(m, off, 64));
    __shared__ float red[4];
    int w = threadIdx.x >> 6;
    if (lane == 0) red[w] = m;
    __syncthreads();
    if (threadIdx.x == 0) {
        m = fmaxf(fmaxf(red[0], red[1]), fmaxf(red[2], red[3]));
        atomicMax(d2mb, __float_as_uint(m));
    }
}

// K4: symmetric fused GEMM, 256x256 tile over the 32x32 triangle grid (528 blocks),
// 8 waves (2M x 4N, wave 128x64, acc 8x4). BK=32, DOUBLE-buffered 64 KB LDS ->
// 2 blocks/CU co-resident (m114 overlap + kills the 3-round tail: 528/512 = 1.03).
// K-step = catalog T3-minimum: stage(t+1) -> compute(t) -> vmcnt(0) -> barrier.
// Epilogue: jmin/anyneg via __ballot (VALU), float sums via shfl -> 3x fewer DS ops.
__global__ __launch_bounds__(512, 4) void kmain(
    const unsigned short* __restrict__ e, const float4* __restrict__ th4,
    const unsigned* __restrict__ d2mb, float* __restrict__ srow,
    unsigned* __restrict__ jminrow, unsigned* __restrict__ negrow) {
    __shared__ __align__(16) char smem[65536];   // 2 bufs x (A 16K + B 16K)

    const int tid  = threadIdx.x;
    const int lane = tid & 63;
    const int w    = tid >> 6;
    const int wr   = w >> 2;          // 0..1 (M 128-half)
    const int wc   = w & 3;           // 0..3 (N 64-slice)

    // XCD-aware bijective swizzle: 528 = 8 x 66
    const int bid = (int)blockIdx.x;
    const int swz = (bid & 7) * 66 + (bid >> 3);
    int rb = (int)((65.0f - sqrtf(4225.0f - 8.0f * (float)swz)) * 0.5f);
    rb = rb < 0 ? 0 : (rb > 31 ? 31 : rb);
    while (tc32(rb + 1) <= swz) rb++;
    while (tc32(rb) > swz) rb--;
    const int cb = rb + (swz - tc32(rb));
    const bool isdiag = (rb == cb);
    const int r0 = rb * 256, c0 = cb * 256;

    // staging (BK=32): per buf, A = 256 rows x 64 B at [0], B likewise at [16384].
    // thread t, pass p: row = (t>>2)+128p, slot = t&3; LDS dest linear tid*16(+8192);
    // global slot pre-swizzled: content(row, s) = global(row, s ^ ((row>>1)&3)).
    const int ssw = (((tid & 3) ^ ((tid >> 3) & 3)) << 3);   // element offset
    const unsigned short* pA0 = e + (size_t)(r0 + (tid >> 2)) * D + ssw;
    const unsigned short* pA1 = e + (size_t)(r0 + 128 + (tid >> 2)) * D + ssw;
    const unsigned short* pB0 = e + (size_t)(c0 + (tid >> 2)) * D + ssw;
    const unsigned short* pB1 = e + (size_t)(c0 + 128 + (tid >> 2)) * D + ssw;

    const int fr = lane & 15;
    const int fq = lane >> 4;
    const int kslot = (fq ^ ((fr >> 1) & 3)) << 4;   // swizzled 16B slot (const/lane)

    f32x4 acc[8][4];
#pragma unroll
    for (int mt = 0; mt < 8; mt++)
#pragma unroll
        for (int nt = 0; nt < 4; nt++) acc[mt][nt] = (f32x4){0.f, 0.f, 0.f, 0.f};

#define STAGE(T, BUF) { \
    const int k0_ = (T) * 32; char* d_ = smem + (BUF) * 32768;   \
    gl_lds16(pA0 + k0_, d_ + tid * 16);                          \
    gl_lds16(pA1 + k0_, d_ + 8192 + tid * 16);                   \
    gl_lds16(pB0 + k0_, d_ + 16384 + tid * 16);                  \
    gl_lds16(pB1 + k0_, d_ + 24576 + tid * 16); }

#define COMPUTE(BUF) { \
    const char* cA_ = smem + (BUF) * 32768;                      \
    const char* cB_ = cA_ + 16384;                               \
    short8 a_[8], b_[4];                                         \
    _Pragma("unroll")                                            \
    for (int mt = 0; mt < 8; mt++)                               \
        a_[mt] = *(const short8*)(cA_ + (wr * 128 + mt * 16 + fr) * 64 + kslot); \
    _Pragma("unroll")                                            \
    for (int nt = 0; nt < 4; nt++)                               \
        b_[nt] = *(const short8*)(cB_ + (wc * 64 + nt * 16 + fr) * 64 + kslot); \
    _Pragma("unroll")                                            \
    for (int mt = 0; mt < 8; mt++)                               \
    _Pragma("unroll")                                            \
    for (int nt = 0; nt < 4; nt++)                               \
        acc[mt][nt] = __builtin_amdgcn_mfma_f32_16x16x32_bf16(   \
            a_[mt], b_[nt], acc[mt][nt], 0, 0, 0); }

#define KST(T)                                                    \
    if ((T) + 1 < 16) STAGE((T) + 1, ((T) + 1) & 1)               \
    COMPUTE((T) & 1)                                              \
    asm volatile("s_waitcnt vmcnt(0)" ::: "memory");              \
    __builtin_amdgcn_s_barrier();                                 \
    __builtin_amdgcn_sched_barrier(0);

    STAGE(0, 0)
    asm volatile("s_waitcnt vmcnt(0)" ::: "memory");
    __builtin_amdgcn_s_barrier();
    __builtin_amdgcn_sched_barrier(0);
    KST(0)  KST(1)  KST(2)  KST(3)
    KST(4)  KST(5)  KST(6)  KST(7)
    KST(8)  KST(9)  KST(10) KST(11)
    KST(12) KST(13) KST(14) KST(15)
#undef KST
#undef COMPUTE
#undef STAGE

    // ---- fused epilogue (acc is the exp2 argument directly) ----
    const float dmax = sqrtf(__uint_as_float(*d2mb)) + 1e-8f;
    const float p2 = 0.0225f * dmax * dmax;
    const float n2 = 0.1225f * dmax * dmax;

    float4*   th_r = (float4*)smem;
    float4*   th_c = (float4*)(smem + 4096);
    float*    rs   = (float*)(smem + 8192);       // [4][256] by wc
    unsigned* rj   = (unsigned*)(smem + 12288);
    unsigned* rn   = (unsigned*)(smem + 16384);
    float*    cs   = (float*)(smem + 20480);      // [2][256] by wr
    unsigned* cj   = (unsigned*)(smem + 22528);
    unsigned* cn   = (unsigned*)(smem + 24576);

    if (tid < 256) th_r[tid] = th4[r0 + tid];
    else           th_c[tid - 256] = th4[c0 + tid - 256];
    __syncthreads();

    const int jbase = wc * 64 + fr;
    const int cbase = c0 + wc * 64;   // column block base for this wave
    float4 thj[4];
#pragma unroll
    for (int nt = 0; nt < 4; nt++) thj[nt] = th_c[jbase + nt * 16];

    float    csum[4]; unsigned cjm[4], cng[4];
#pragma unroll
    for (int nt = 0; nt < 4; nt++) { csum[nt] = 0.0f; cjm[nt] = 0xFFFFFFFFu; cng[nt] = 0u; }

    const int ilb = wr * 128 + fq * 4;
#pragma unroll
    for (int mt = 0; mt < 8; mt++) {
#pragma unroll
        for (int rr = 0; rr < 4; rr++) {
            const int il = ilb + mt * 16 + rr;
            const int i  = r0 + il;
            const float4 ti = th_r[il];
            float sv = 0.0f; unsigned jv = 0xFFFFFFFFu; unsigned nv = 0u;
#pragma unroll
            for (int nt = 0; nt < 4; nt++) {
                const int j = cbase + nt * 16 + fr;
                const float4 tj = thj[nt];
                float dot = ti.x * tj.x + ti.y * tj.y + ti.z * tj.z;
                float d2 = fmaf(-2.0f, dot, ti.w + tj.w);
                bool pos = isdiag ? ((d2 < p2) && (j != i)) : (d2 < p2);
                bool neg = (d2 > n2);
                float c = (pos || neg) ? exp2f(acc[mt][nt][rr]) : 0.0f;
                sv += c;
                // wave-wide masks: bit l = (fq=l>>4 row, fr=l&15 col)
                unsigned long long bp = __ballot(pos);
                unsigned long long bn = __ballot(neg);
                // row-side (my fq row): pos/neg bits over the 16 fr-columns
                unsigned fp = (unsigned)((bp >> (fq << 4)) & 0xFFFFull);
                unsigned fn = (unsigned)((bn >> (fq << 4)) & 0xFFFFull);
                if (fp) jv = min(jv, (unsigned)(cbase + nt * 16 + __builtin_ctz(fp)));
                nv |= (fn != 0u) ? 1u : 0u;
                if (!isdiag) {
                    csum[nt] += c;
                    // col-side (my fr column): bits {fr, fr+16, fr+32, fr+48} = rows fq 0..3
                    unsigned long long m4p = (bp >> fr) & 0x0001000100010001ull;
                    unsigned long long m4n = (bn >> fr) & 0x0001000100010001ull;
                    if (m4p) {
                        int fqs = __builtin_ctzll(m4p) >> 4;
                        cjm[nt] = min(cjm[nt],
                                      (unsigned)(r0 + wr * 128 + mt * 16 + rr + 4 * fqs));
                    }
                    cng[nt] |= (m4n != 0ull) ? 1u : 0u;
                }
            }
            // row-side float reduce over 16 fr-lanes (jv/nv already row-complete)
#pragma unroll
            for (int off = 1; off < 16; off <<= 1) sv += __shfl_xor(sv, off, 64);
            if (fr == 0) {
                rs[wc * 256 + il] = sv;
                rj[wc * 256 + il] = jv;
                rn[wc * 256 + il] = nv;
            }
        }
    }

    // column-side float reduce over the 4 fq groups (cjm/cng already col-complete)
    if (!isdiag) {
#pragma unroll
        for (int nt = 0; nt < 4; nt++) {
            float sv = csum[nt];
            sv += __shfl_xor(sv, 16, 64);
            sv += __shfl_xor(sv, 32, 64);
            if (fq == 0) {
                const int jl = jbase + nt * 16;
                cs[wr * 256 + jl] = sv;
                cj[wr * 256 + jl] = cjm[nt];
                cn[wr * 256 + jl] = cng[nt];
            }
        }
    }
    __syncthreads();
    if (tid < 256) {
        float    sv = rs[tid] + rs[256 + tid] + rs[512 + tid] + rs[768 + tid];
        unsigned jv = min(min(rj[tid], rj[256 + tid]), min(rj[512 + tid], rj[768 + tid]));
        unsigned nv = rn[tid] | rn[256 + tid] | rn[512 + tid] | rn[768 + tid];
        atomicAdd(&srow[r0 + tid], sv);
        atomicMin(&jminrow[r0 + tid], jv);
        atomicOr(&negrow[r0 + tid], nv);
    } else if (!isdiag) {
        const int t2 = tid - 256;
        float    cv = cs[t2] + cs[256 + t2];
        unsigned jj = min(cj[t2], cj[256 + t2]);
        unsigned nn = cn[t2] | cn[256 + t2];
        atomicAdd(&srow[c0 + t2], cv);
        atomicMin(&jminrow[c0 + t2], jj);
        atomicOr(&negrow[c0 + t2], nn);
    }
}

// K5: per-row finalize. e is pre-scaled: sim = dot_scaled * ln2.
__global__ void krow(const unsigned short* __restrict__ e, const float* __restrict__ srow,
                     const unsigned* __restrict__ jminrow, const unsigned* __restrict__ negrow,
                     float* __restrict__ pr, float* __restrict__ vf) {
    int row  = blockIdx.x * 4 + (threadIdx.x >> 6);
    int lane = threadIdx.x & 63;
    unsigned jmv = jminrow[row];
    bool valid = (jmv != 0xFFFFFFFFu) && (negrow[row] != 0u);
    float p = 0.0f;
    if (valid) {
        const uint4* a = (const uint4*)(e + (size_t)row * D);
        const uint4* b = (const uint4*)(e + (size_t)jmv * D);
        uint4 va = a[lane], vb = b[lane];
        float dot = 0.0f;
        dot += bf2f(va.x & 0xFFFFu) * bf2f(vb.x & 0xFFFFu);
        dot += bf2f(va.x >> 16)     * bf2f(vb.x >> 16);
        dot += bf2f(va.y & 0xFFFFu) * bf2f(vb.y & 0xFFFFu);
        dot += bf2f(va.y >> 16)     * bf2f(vb.y >> 16);
        dot += bf2f(va.z & 0xFFFFu) * bf2f(vb.z & 0xFFFFu);
        dot += bf2f(va.z >> 16)     * bf2f(vb.z >> 16);
        dot += bf2f(va.w & 0xFFFFu) * bf2f(vb.w & 0xFFFFu);
        dot += bf2f(va.w >> 16)     * bf2f(vb.w >> 16);
#pragma unroll
        for (int off = 1; off < 64; off <<= 1) dot += __shfl_xor(dot, off, 64);
        p = logf(srow[row]) - dot * 0.69314718f;
    }
    if (lane == 0) { pr[row] = p; vf[row] = valid ? 1.0f : 0.0f; }
}

// K6: deterministic fixed-tree reduction -> scalar loss.
__global__ void kfinal(const float* __restrict__ pr, const float* __restrict__ vf,
                       float* __restrict__ out) {
    __shared__ float ls[1024];
    __shared__ float lc[1024];
    int t = threadIdx.x;
    float sv = 0.0f, cv = 0.0f;
#pragma unroll
    for (int k = 0; k < 8; k++) { sv += pr[t * 8 + k]; cv += vf[t * 8 + k]; }
    ls[t] = sv; lc[t] = cv;
    __syncthreads();
    for (int off = 512; off > 0; off >>= 1) {
        if (t < off) { ls[t] += ls[t + off]; lc[t] += lc[t + off]; }
        __syncthreads();
    }
    if (t == 0) out[0] = (lc[0] > 0.0f) ? (ls[0] / lc[0]) : 0.0f;
}

extern "C" void kernel_launch(void* const* d_in, const int* in_sizes, int n_in,
                              void* d_out, int out_size, void* d_ws, size_t ws_size,
                              hipStream_t stream) {
    const float* emb = (const float*)d_in[0];
    const float* th  = (const float*)d_in[1];
    float* out = (float*)d_out;
    char* ws = (char*)d_ws;

    unsigned short* e    = (unsigned short*)(ws);
    float4*   th4        = (float4*)(ws + 8388608);
    float*    srow       = (float*)(ws + 8519680);
    unsigned* jminr      = (unsigned*)(ws + 8552448);
    unsigned* negr       = (unsigned*)(ws + 8585216);
    float*    pr         = (float*)(ws + 8617984);
    float*    vf         = (float*)(ws + 8650752);
    unsigned* d2mb       = (unsigned*)(ws + 8683520);

    knorm<<<N / 4, 256, 0, stream>>>(emb, e, th, th4, srow, jminr, negr, d2mb);
    kd2max<<<256, 256, 0, stream>>>(th4, d2mb);
    kmain<<<528, 512, 0, stream>>>(e, th4, d2mb, srow, jminr, negr);
    krow<<<N / 4, 256, 0, stream>>>(e, srow, jminr, negr, pr, vf);
    kfinal<<<1, 1024, 0, stream>>>(pr, vf, out);
}

// Round 10
// 241.812 us; speedup vs baseline: 1.7927x; 1.7927x over previous
//
#include <hip/hip_runtime.h>

#define N 8192
#define D 512

typedef __attribute__((ext_vector_type(8))) short short8;
typedef __attribute__((ext_vector_type(4))) float f32x4;

static __device__ __forceinline__ unsigned short f2bf(float f) {
    unsigned u = __float_as_uint(f);
    unsigned r = (u + 0x7FFFu + ((u >> 16) & 1u)) >> 16;
    return (unsigned short)r;
}
static __device__ __forceinline__ float bf2f(unsigned u) {
    return __uint_as_float(u << 16);
}
// triangle cumulative for 64x64 tile grid (128-wide tiles): row r owns (64-r) tiles
static __device__ __forceinline__ int tc64(int r) { return r * (129 - r) / 2; }

// K0: pack thetas -> float4 (x,y,z,|t|^2); init per-row accumulators + d2max.
__global__ void kpack(const float* __restrict__ th, float4* __restrict__ th4,
                      float* __restrict__ srow, unsigned* __restrict__ jminrow,
                      unsigned* __restrict__ negrow, unsigned* __restrict__ d2mb) {
    int i = blockIdx.x * 256 + threadIdx.x;
    if (i < N) {
        float x = th[3 * i], y = th[3 * i + 1], z = th[3 * i + 2];
        float4 v; v.x = x; v.y = y; v.z = z; v.w = x * x + y * y + z * z;
        th4[i] = v;
        srow[i] = 0.0f;
        jminrow[i] = 0xFFFFFFFFu;
        negrow[i] = 0u;
    }
    if (i == 0) *d2mb = 0u;
}

// K1: row-normalize embeddings -> bf16 e[N][D], PRE-SCALED by sqrt(10*log2(e)).
// Blocks 0..255 additionally compute the global theta-d2max (th4 ready via kpack).
__global__ void knorm(const float* __restrict__ emb, unsigned short* __restrict__ e,
                      const float4* __restrict__ th4, unsigned* __restrict__ d2mb) {
    int w    = threadIdx.x >> 6;
    int row  = blockIdx.x * 4 + w;
    int lane = threadIdx.x & 63;
    const float4* src = (const float4*)(emb + (size_t)row * D);
    float4 v0 = src[lane * 2];
    float4 v1 = src[lane * 2 + 1];
    float ss = v0.x*v0.x + v0.y*v0.y + v0.z*v0.z + v0.w*v0.w
             + v1.x*v1.x + v1.y*v1.y + v1.z*v1.z + v1.w*v1.w;
#pragma unroll
    for (int off = 1; off < 64; off <<= 1) ss += __shfl_xor(ss, off, 64);
    // 3.7982826^2 = 14.42695 = 10*log2(e): acc becomes exp2 argument directly
    float inv = 3.7982826f / fmaxf(sqrtf(ss), 1e-12f);
    unsigned short h0 = f2bf(v0.x * inv), h1 = f2bf(v0.y * inv);
    unsigned short h2 = f2bf(v0.z * inv), h3 = f2bf(v0.w * inv);
    unsigned short h4 = f2bf(v1.x * inv), h5 = f2bf(v1.y * inv);
    unsigned short h6 = f2bf(v1.z * inv), h7 = f2bf(v1.w * inv);
    uint4 pk;
    pk.x = (unsigned)h0 | ((unsigned)h1 << 16);
    pk.y = (unsigned)h2 | ((unsigned)h3 << 16);
    pk.z = (unsigned)h4 | ((unsigned)h5 << 16);
    pk.w = (unsigned)h6 | ((unsigned)h7 << 16);
    ((uint4*)(e + (size_t)row * D))[lane] = pk;

    // fused d2max: first 256 blocks, one wave owns 8 theta rows (quad + mirror)
    if (blockIdx.x < 256) {
        int widx = blockIdx.x * 4 + w;
        int q0 = widx * 4;
        int m0 = N - 4 - q0;
        float4 a0 = th4[q0], a1 = th4[q0 + 1], a2 = th4[q0 + 2], a3 = th4[q0 + 3];
        float4 b0 = th4[m0], b1 = th4[m0 + 1], b2 = th4[m0 + 2], b3 = th4[m0 + 3];
        float m = 0.0f;
        for (int j = q0 + 1 + lane; j < N; j += 64) {
            float4 tj = th4[j];
            float d;
            d = a0.w + tj.w - 2.0f * (a0.x*tj.x + a0.y*tj.y + a0.z*tj.z); m = fmaxf(m, d);
            d = a1.w + tj.w - 2.0f * (a1.x*tj.x + a1.y*tj.y + a1.z*tj.z); m = fmaxf(m, d);
            d = a2.w + tj.w - 2.0f * (a2.x*tj.x + a2.y*tj.y + a2.z*tj.z); m = fmaxf(m, d);
            d = a3.w + tj.w - 2.0f * (a3.x*tj.x + a3.y*tj.y + a3.z*tj.z); m = fmaxf(m, d);
        }
        for (int j = m0 + 1 + lane; j < N; j += 64) {
            float4 tj = th4[j];
            float d;
            d = b0.w + tj.w - 2.0f * (b0.x*tj.x + b0.y*tj.y + b0.z*tj.z); m = fmaxf(m, d);
            d = b1.w + tj.w - 2.0f * (b1.x*tj.x + b1.y*tj.y + b1.z*tj.z); m = fmaxf(m, d);
            d = b2.w + tj.w - 2.0f * (b2.x*tj.x + b2.y*tj.y + b2.z*tj.z); m = fmaxf(m, d);
            d = b3.w + tj.w - 2.0f * (b3.x*tj.x + b3.y*tj.y + b3.z*tj.z); m = fmaxf(m, d);
        }
#pragma unroll
        for (int off = 1; off < 64; off <<= 1) m = fmaxf(m, __shfl_xor(m, off, 64));
        if (lane == 0) atomicMax(d2mb, __float_as_uint(m));
    }
}

// K4: symmetric fused GEMM over the 64x64 upper-triangle of 128x128 tiles
// (2080 blocks = 8 XCD x 260). 256 threads = 4 waves, wave = 32 rows x 128 cols,
// acc[2][8]. NO LDS staging, NO lockstep: fragments load straight from global
// (matrix is 8 MB, L2/L3-resident); latency hidden by ~3 co-resident blocks/CU
// of free-running waves (m114 mechanism). Raw s_barrier every 4 K-steps only to
// bound wave drift for L1 B-reuse. Epilogue: ballot masks + direct row atomics.
__global__ __launch_bounds__(256) void kmain(
    const unsigned short* __restrict__ e, const float4* __restrict__ th4,
    const unsigned* __restrict__ d2mb, float* __restrict__ srow,
    unsigned* __restrict__ jminrow, unsigned* __restrict__ negrow) {
    const int tid  = threadIdx.x;
    const int lane = tid & 63;
    const int w    = tid >> 6;        // 0..3: wave owns rows w*32..w*32+31
    const int fr   = lane & 15;
    const int fq   = lane >> 4;

    // XCD-aware bijective swizzle + triangle decode (64-row grid)
    const int bid = (int)blockIdx.x;
    const int swz = (bid & 7) * 260 + (bid >> 3);
    int rb = (int)((129.0f - sqrtf(16641.0f - 8.0f * (float)swz)) * 0.5f);
    rb = rb < 0 ? 0 : (rb > 63 ? 63 : rb);
    while (tc64(rb + 1) <= swz) rb++;
    while (tc64(rb) > swz) rb--;
    const int cb = rb + (swz - tc64(rb));
    const bool isdiag = (rb == cb);
    const int r0 = rb * 128, c0 = cb * 128;

    const unsigned short* Abase = e + (size_t)(r0 + w * 32 + fr) * D + fq * 8;
    const unsigned short* Bbase = e + (size_t)(c0 + fr) * D + fq * 8;

    f32x4 acc[2][8];
#pragma unroll
    for (int mt = 0; mt < 2; mt++)
#pragma unroll
        for (int nt = 0; nt < 8; nt++) acc[mt][nt] = (f32x4){0.f, 0.f, 0.f, 0.f};

    for (int ko = 0; ko < 4; ++ko) {
#pragma unroll
        for (int ki = 0; ki < 4; ++ki) {
            const int kk = (ko * 4 + ki) * 32;
            short8 a0 = *(const short8*)(Abase + kk);
            short8 a1 = *(const short8*)(Abase + 16 * D + kk);
            short8 b[8];
#pragma unroll
            for (int nt = 0; nt < 8; nt++)
                b[nt] = *(const short8*)(Bbase + nt * 16 * D + kk);
#pragma unroll
            for (int nt = 0; nt < 8; nt++) {
                acc[0][nt] = __builtin_amdgcn_mfma_f32_16x16x32_bf16(a0, b[nt], acc[0][nt], 0, 0, 0);
                acc[1][nt] = __builtin_amdgcn_mfma_f32_16x16x32_bf16(a1, b[nt], acc[1][nt], 0, 0, 0);
            }
        }
        __builtin_amdgcn_s_barrier();   // drift bound only; no memory drain
    }

    // ---- fused epilogue (acc is the exp2 argument directly) ----
    const float dmax = sqrtf(__uint_as_float(*d2mb)) + 1e-8f;
    const float p2 = 0.0225f * dmax * dmax;
    const float n2 = 0.1225f * dmax * dmax;

    __shared__ float4   th_r[128];
    __shared__ float4   th_c[128];
    __shared__ float    cs[4][128];
    __shared__ unsigned cj[4][128];
    __shared__ unsigned cn[4][128];

    if (tid < 128) th_r[tid] = th4[r0 + tid];
    else           th_c[tid - 128] = th4[c0 + tid - 128];
    __syncthreads();

    float4 thj[8];
#pragma unroll
    for (int nt = 0; nt < 8; nt++) thj[nt] = th_c[nt * 16 + fr];

    float    csum[8]; unsigned cjm[8], cng[8];
#pragma unroll
    for (int nt = 0; nt < 8; nt++) { csum[nt] = 0.0f; cjm[nt] = 0xFFFFFFFFu; cng[nt] = 0u; }

#pragma unroll
    for (int mt = 0; mt < 2; mt++) {
#pragma unroll
        for (int rr = 0; rr < 4; rr++) {
            const int il = w * 32 + mt * 16 + fq * 4 + rr;
            const int i  = r0 + il;
            const float4 ti = th_r[il];
            float sv = 0.0f; unsigned jv = 0xFFFFFFFFu; unsigned nv = 0u;
#pragma unroll
            for (int nt = 0; nt < 8; nt++) {
                const int j = c0 + nt * 16 + fr;
                const float4 tj = thj[nt];
                float dot = ti.x * tj.x + ti.y * tj.y + ti.z * tj.z;
                float d2 = fmaf(-2.0f, dot, ti.w + tj.w);
                bool pos = isdiag ? ((d2 < p2) && (j != i)) : (d2 < p2);
                bool neg = (d2 > n2);
                float c = (pos || neg) ? exp2f(acc[mt][nt][rr]) : 0.0f;
                sv += c;
                unsigned long long bp = __ballot(pos);
                unsigned long long bn = __ballot(neg);
                // row-side: my fq row's 16 column bits
                unsigned fp = (unsigned)((bp >> (fq << 4)) & 0xFFFFull);
                unsigned fn = (unsigned)((bn >> (fq << 4)) & 0xFFFFull);
                if (fp) jv = min(jv, (unsigned)(c0 + nt * 16 + __builtin_ctz(fp)));
                nv |= (fn != 0u) ? 1u : 0u;
                if (!isdiag) {
                    csum[nt] += c;
                    // col-side: my fr column's bits at rows fq=0..3
                    unsigned long long m4p = (bp >> fr) & 0x0001000100010001ull;
                    unsigned long long m4n = (bn >> fr) & 0x0001000100010001ull;
                    if (m4p) {
                        int fqs = __builtin_ctzll(m4p) >> 4;
                        cjm[nt] = min(cjm[nt],
                                      (unsigned)(r0 + w * 32 + mt * 16 + rr + 4 * fqs));
                    }
                    cng[nt] |= (m4n != 0ull) ? 1u : 0u;
                }
            }
            // row-side float reduce over 16 fr-lanes; then direct atomics
#pragma unroll
            for (int off = 1; off < 16; off <<= 1) sv += __shfl_xor(sv, off, 64);
            if (fr == 0) {
                atomicAdd(&srow[i], sv);
                atomicMin(&jminrow[i], jv);
                atomicOr(&negrow[i], nv);
            }
        }
    }

    // column-side: cross-fq reduce, stash per-wave, combine, atomics
    if (!isdiag) {
#pragma unroll
        for (int nt = 0; nt < 8; nt++) {
            float sv = csum[nt];
            sv += __shfl_xor(sv, 16, 64);
            sv += __shfl_xor(sv, 32, 64);
            if (fq == 0) {
                cs[w][nt * 16 + fr] = sv;
                cj[w][nt * 16 + fr] = cjm[nt];
                cn[w][nt * 16 + fr] = cng[nt];
            }
        }
        __syncthreads();
        if (tid < 128) {
            float    cv = cs[0][tid] + cs[1][tid] + cs[2][tid] + cs[3][tid];
            unsigned jj = min(min(cj[0][tid], cj[1][tid]), min(cj[2][tid], cj[3][tid]));
            unsigned nn = cn[0][tid] | cn[1][tid] | cn[2][tid] | cn[3][tid];
            atomicAdd(&srow[c0 + tid], cv);
            atomicMin(&jminrow[c0 + tid], jj);
            atomicOr(&negrow[c0 + tid], nn);
        }
    }
}

// K5: per-row finalize. e is pre-scaled: sim = dot_scaled * ln2.
__global__ void krow(const unsigned short* __restrict__ e, const float* __restrict__ srow,
                     const unsigned* __restrict__ jminrow, const unsigned* __restrict__ negrow,
                     float* __restrict__ pr, float* __restrict__ vf) {
    int row  = blockIdx.x * 4 + (threadIdx.x >> 6);
    int lane = threadIdx.x & 63;
    unsigned jmv = jminrow[row];
    bool valid = (jmv != 0xFFFFFFFFu) && (negrow[row] != 0u);
    float p = 0.0f;
    if (valid) {
        const uint4* a = (const uint4*)(e + (size_t)row * D);
        const uint4* b = (const uint4*)(e + (size_t)jmv * D);
        uint4 va = a[lane], vb = b[lane];
        float dot = 0.0f;
        dot += bf2f(va.x & 0xFFFFu) * bf2f(vb.x & 0xFFFFu);
        dot += bf2f(va.x >> 16)     * bf2f(vb.x >> 16);
        dot += bf2f(va.y & 0xFFFFu) * bf2f(vb.y & 0xFFFFu);
        dot += bf2f(va.y >> 16)     * bf2f(vb.y >> 16);
        dot += bf2f(va.z & 0xFFFFu) * bf2f(vb.z & 0xFFFFu);
        dot += bf2f(va.z >> 16)     * bf2f(vb.z >> 16);
        dot += bf2f(va.w & 0xFFFFu) * bf2f(vb.w & 0xFFFFu);
        dot += bf2f(va.w >> 16)     * bf2f(vb.w >> 16);
#pragma unroll
        for (int off = 1; off < 64; off <<= 1) dot += __shfl_xor(dot, off, 64);
        p = logf(srow[row]) - dot * 0.69314718f;
    }
    if (lane == 0) { pr[row] = p; vf[row] = valid ? 1.0f : 0.0f; }
}

// K6: deterministic fixed-tree reduction -> scalar loss.
__global__ void kfinal(const float* __restrict__ pr, const float* __restrict__ vf,
                       float* __restrict__ out) {
    __shared__ float ls[1024];
    __shared__ float lc[1024];
    int t = threadIdx.x;
    float sv = 0.0f, cv = 0.0f;
#pragma unroll
    for (int k = 0; k < 8; k++) { sv += pr[t * 8 + k]; cv += vf[t * 8 + k]; }
    ls[t] = sv; lc[t] = cv;
    __syncthreads();
    for (int off = 512; off > 0; off >>= 1) {
        if (t < off) { ls[t] += ls[t + off]; lc[t] += lc[t + off]; }
        __syncthreads();
    }
    if (t == 0) out[0] = (lc[0] > 0.0f) ? (ls[0] / lc[0]) : 0.0f;
}

extern "C" void kernel_launch(void* const* d_in, const int* in_sizes, int n_in,
                              void* d_out, int out_size, void* d_ws, size_t ws_size,
                              hipStream_t stream) {
    const float* emb = (const float*)d_in[0];
    const float* th  = (const float*)d_in[1];
    float* out = (float*)d_out;
    char* ws = (char*)d_ws;

    unsigned short* e    = (unsigned short*)(ws);
    float4*   th4        = (float4*)(ws + 8388608);
    float*    srow       = (float*)(ws + 8519680);
    unsigned* jminr      = (unsigned*)(ws + 8552448);
    unsigned* negr       = (unsigned*)(ws + 8585216);
    float*    pr         = (float*)(ws + 8617984);
    float*    vf         = (float*)(ws + 8650752);
    unsigned* d2mb       = (unsigned*)(ws + 8683520);

    kpack<<<32, 256, 0, stream>>>(th, th4, srow, jminr, negr, d2mb);
    knorm<<<N / 4, 256, 0, stream>>>(emb, e, th4, d2mb);
    kmain<<<2080, 256, 0, stream>>>(e, th4, d2mb, srow, jminr, negr);
    krow<<<N / 4, 256, 0, stream>>>(e, srow, jminr, negr, pr, vf);
    kfinal<<<1, 1024, 0, stream>>>(pr, vf, out);
}